// Round 6
// baseline (2416.106 us; speedup 1.0000x reference)
//
#include <hip/hip_runtime.h>

// LightGCN propagation, 3 bipartite graphs. Round 6: fix round-5's ragged
// launch-guard bug (first pair must be guarded by i < stride2, not i < H;
// the tail threads double-processed ~255 pairs -> corrupted deg + cursor
// overflow). Structure otherwise identical to round 5:
//  * rows = concat(r, c+nA), cols = concat(c+nA, r)  (mirrored bipartite) ->
//    read only first E/2 pairs, emit both directions; 2 pairs/thread -> 4
//    scattered writes in flight.
//  * vals[e] = isq[rows[e]]*isq[cols[e]], deg = histogram -> value-free CSR;
//    curS stored pre-scaled by isq.

constexpr int EMB = 64;
constexpr float THIRD = 1.0f / 3.0f;
constexpr float EPS_NRM = 1e-12f;
constexpr float EPS_LAP = 1e-8f;
constexpr int SCAN_BLOCK = 256;
constexpr int SCAN_ITEMS = 8;        // per thread
constexpr int SCAN_TILE = SCAN_BLOCK * SCAN_ITEMS;  // 2048

// curS = isq .* concat(fA,fB); acc = concat(fA,fB)/3
__global__ void init_concat_kernel(const float* __restrict__ fA,
                                   const float* __restrict__ fB,
                                   const float* __restrict__ isq,
                                   int nA, int N,
                                   float* __restrict__ curS,
                                   float* __restrict__ acc) {
    long long total = (long long)N * (EMB / 4);
    long long stride = (long long)gridDim.x * blockDim.x;
    long long iA = (long long)nA * (EMB / 4);
    for (long long i = blockIdx.x * (long long)blockDim.x + threadIdx.x;
         i < total; i += stride) {
        float4 v = (i < iA) ? ((const float4*)fA)[i] : ((const float4*)fB)[i - iA];
        float q = isq[i >> 4];
        ((float4*)curS)[i] = make_float4(v.x * q, v.y * q, v.z * q, v.w * q);
        ((float4*)acc)[i] = make_float4(v.x * THIRD, v.y * THIRD, v.z * THIRD, v.w * THIRD);
    }
}

// Histogram over both endpoints of the first-half pairs (covers the full
// symmetric edge set). 2 pairs per thread for atomic MLP.
__global__ void hist_kernel(const int* __restrict__ rowsH,
                            const int* __restrict__ colsH,
                            long long H, long long stride2,
                            int* __restrict__ cnt) {
    long long i = blockIdx.x * (long long)blockDim.x + threadIdx.x;
    if (i < stride2) {                 // FIX: was (i < H) -> double-processing
        int r0 = rowsH[i];
        int c0 = colsH[i];
        atomicAdd(&cnt[r0], 1);
        atomicAdd(&cnt[c0], 1);
        long long j = i + stride2;
        if (j < H) {
            int r1 = rowsH[j];
            int c1 = colsH[j];
            atomicAdd(&cnt[r1], 1);
            atomicAdd(&cnt[c1], 1);
        }
    }
}

// --- two-level scan ---------------------------------------------------------
__global__ void scan_partial_kernel(const int* __restrict__ cnt, int N,
                                    int* __restrict__ bsum) {
    __shared__ int red[SCAN_BLOCK];
    const int b = blockIdx.x;
    const int t = threadIdx.x;
    const int base = b * SCAN_TILE + t * SCAN_ITEMS;
    int s = 0;
    if (base + SCAN_ITEMS <= N) {
        int4 a = ((const int4*)cnt)[(base >> 2) + 0];
        int4 c = ((const int4*)cnt)[(base >> 2) + 1];
        s = a.x + a.y + a.z + a.w + c.x + c.y + c.z + c.w;
    } else {
        for (int k = 0; k < SCAN_ITEMS; ++k)
            if (base + k < N) s += cnt[base + k];
    }
    red[t] = s;
    __syncthreads();
    for (int off = SCAN_BLOCK / 2; off > 0; off >>= 1) {
        if (t < off) red[t] += red[t + off];
        __syncthreads();
    }
    if (t == 0) bsum[b] = red[0];
}

__global__ void scan_bsums_kernel(int* __restrict__ bsum, int NB) {
    __shared__ int s[1024];
    const int t = threadIdx.x;
    int v = (t < NB) ? bsum[t] : 0;
    s[t] = v;
    __syncthreads();
    for (int off = 1; off < 1024; off <<= 1) {
        int x = (t >= off) ? s[t - off] : 0;
        __syncthreads();
        s[t] += x;
        __syncthreads();
    }
    if (t < NB) bsum[t] = s[t] - v;      // exclusive prefix
    if (t == 1023) bsum[NB] = s[1023];   // total
}

__global__ void scan_apply_kernel(int* __restrict__ cnt, int N,
                                  const int* __restrict__ bsum, int NB,
                                  int* __restrict__ ptr,
                                  float* __restrict__ isq) {
    __shared__ int tsum[SCAN_BLOCK];
    const int b = blockIdx.x;
    const int t = threadIdx.x;
    const int base = b * SCAN_TILE + t * SCAN_ITEMS;
    int v[SCAN_ITEMS];
    int s = 0;
    if (base + SCAN_ITEMS <= N) {
        int4 a = ((const int4*)cnt)[(base >> 2) + 0];
        int4 c = ((const int4*)cnt)[(base >> 2) + 1];
        v[0] = a.x; v[1] = a.y; v[2] = a.z; v[3] = a.w;
        v[4] = c.x; v[5] = c.y; v[6] = c.z; v[7] = c.w;
        s = v[0] + v[1] + v[2] + v[3] + v[4] + v[5] + v[6] + v[7];
    } else {
        for (int k = 0; k < SCAN_ITEMS; ++k) {
            v[k] = (base + k < N) ? cnt[base + k] : 0;
            s += v[k];
        }
    }
    tsum[t] = s;
    __syncthreads();
    for (int off = 1; off < SCAN_BLOCK; off <<= 1) {
        int x = (t >= off) ? tsum[t - off] : 0;
        __syncthreads();
        tsum[t] += x;
        __syncthreads();
    }
    int run = bsum[b] + tsum[t] - s;     // exclusive offset for this thread
    for (int k = 0; k < SCAN_ITEMS; ++k) {
        if (base + k < N) {
            ptr[base + k] = run;
            cnt[base + k] = run;         // scatter cursor
            isq[base + k] = 1.0f / (sqrtf((float)v[k]) + EPS_LAP);
            run += v[k];
        }
    }
    if (b == 0 && t == 0) ptr[N] = bsum[NB];
}
// ----------------------------------------------------------------------------

// Scatter both directions of each first-half pair: ci[cur[r]++]=c and
// ci[cur[c]++]=r. 2 pairs per thread -> 4 atomics + 4 scattered writes in
// flight.
__global__ void scatter_kernel(const int* __restrict__ rowsH,
                               const int* __restrict__ colsH,
                               long long H, long long stride2,
                               int* __restrict__ cursor,
                               int* __restrict__ ci) {
    long long i = blockIdx.x * (long long)blockDim.x + threadIdx.x;
    if (i >= stride2) return;          // FIX: was (i < H) -> double-processing
    long long j = i + stride2;
    bool do1 = (j < H);
    int r0 = rowsH[i];
    int c0 = colsH[i];
    int r1 = 0, c1 = 0;
    if (do1) { r1 = rowsH[j]; c1 = colsH[j]; }
    int p0 = atomicAdd(&cursor[r0], 1);
    int p1 = atomicAdd(&cursor[c0], 1);
    int p2 = 0, p3 = 0;
    if (do1) {
        p2 = atomicAdd(&cursor[r1], 1);
        p3 = atomicAdd(&cursor[c1], 1);
    }
    ci[p0] = c0;
    ci[p1] = r0;
    if (do1) {
        ci[p2] = c1;
        ci[p3] = r1;
    }
}

// One wave (64 lanes) per output row; lane owns one of the 64 dims.
// s = sum of curS over CSR neighbors (2-way unrolled gathers);
// raw = isq[r]*s; fused row-L2-norm (full-wave shfl reduce) + acc update;
// optional next-layer pre-scaled write nxtS = isq[r]*raw.
__global__ void spmm_norm_kernel(const int* __restrict__ ptr,
                                 const int* __restrict__ ci,
                                 const float* __restrict__ isq,
                                 const float* __restrict__ curS,
                                 float* __restrict__ nxtS,
                                 float* __restrict__ acc,
                                 int N, int writeNext) {
    int gid = (int)((blockIdx.x * (long long)blockDim.x + threadIdx.x) >> 6);
    int lane = threadIdx.x & 63;
    if (gid >= N) return;
    const int beg = ptr[gid];
    const int end = ptr[gid + 1];
    float s = 0.0f;
    int j = beg;
    for (; j + 2 <= end; j += 2) {
        int c0 = ci[j];
        int c1 = ci[j + 1];
        float g0 = curS[(long long)c0 * EMB + lane];
        float g1 = curS[(long long)c1 * EMB + lane];
        s += g0;
        s += g1;
    }
    if (j < end) {
        s += curS[(long long)ci[j] * EMB + lane];
    }
    const float q = isq[gid];
    float raw = s * q;
    float ss = raw * raw;
    ss += __shfl_xor(ss, 1, 64);
    ss += __shfl_xor(ss, 2, 64);
    ss += __shfl_xor(ss, 4, 64);
    ss += __shfl_xor(ss, 8, 64);
    ss += __shfl_xor(ss, 16, 64);
    ss += __shfl_xor(ss, 32, 64);
    const long long idx = (long long)gid * EMB + lane;
    if (writeNext) nxtS[idx] = raw * q;
    float scale = THIRD / fmaxf(sqrtf(ss), EPS_NRM);
    acc[idx] += raw * scale;
}

static inline int grid_for(long long total, int block) {
    long long g = (total + block - 1) / block;
    if (g > (1LL << 20)) g = (1LL << 20);
    if (g < 1) g = 1;
    return (int)g;
}

extern "C" void kernel_launch(void* const* d_in, const int* in_sizes, int n_in,
                              void* d_out, int out_size, void* d_ws, size_t ws_size,
                              hipStream_t stream) {
    const float* fu = (const float*)d_in[0];
    const float* fb = (const float*)d_in[1];
    const float* fi = (const float*)d_in[2];
    const int nU = in_sizes[0] / EMB;
    const int nB = in_sizes[1] / EMB;
    const int nI = in_sizes[2] / EMB;
    float* out = (float*)d_out;

    struct G {
        const int* rows; const int* cols;
        long long E; const float* fA; const float* fB; int nA; int nBn;
    };
    G gs[3] = {
        { (const int*)d_in[3], (const int*)d_in[4],
          (long long)in_sizes[3], fu, fb, nU, nB },
        { (const int*)d_in[6], (const int*)d_in[7],
          (long long)in_sizes[6], fu, fi, nU, nI },
        { (const int*)d_in[9], (const int*)d_in[10],
          (long long)in_sizes[9], fb, fi, nB, nI },
    };

    int maxN = 0;
    long long maxE = 0;
    for (int gi = 0; gi < 3; ++gi) {
        int N = gs[gi].nA + gs[gi].nBn;
        if (N > maxN) maxN = N;
        if (gs[gi].E > maxE) maxE = gs[gi].E;
    }
    const int maxNB = (maxN + SCAN_TILE - 1) / SCAN_TILE;

    // Workspace layout (16B-aligned chunks):
    char* w = (char*)d_ws;
    float* buf0 = (float*)w;                 w += (size_t)maxN * EMB * sizeof(float);
    float* buf1 = (float*)w;                 w += (size_t)maxN * EMB * sizeof(float);
    int* ptr = (int*)w;                      w += (size_t)((maxN + 8) & ~7) * sizeof(int);
    int* cnt = (int*)w;                      w += (size_t)((maxN + 8) & ~7) * sizeof(int);
    float* isq = (float*)w;                  w += (size_t)((maxN + 8) & ~7) * sizeof(float);
    int* bsum = (int*)w;                     w += (size_t)((maxNB + 8) & ~7) * sizeof(int);
    int* ci = (int*)w;

    long long out_off = 0;
    for (int gi = 0; gi < 3; ++gi) {
        const G& g = gs[gi];
        const int N = g.nA + g.nBn;
        const int NB = (N + SCAN_TILE - 1) / SCAN_TILE;
        float* acc = out + out_off;
        const long long H = g.E / 2;               // first-half (mirror) pairs
        const long long stride2 = (H + 1) / 2;     // 2 pairs per thread

        // --- CSR build (value-free, mirror-aware) ---
        hipMemsetAsync(cnt, 0, (size_t)N * sizeof(int), stream);
        hist_kernel<<<grid_for(stride2, 256), 256, 0, stream>>>(
            g.rows, g.cols, H, stride2, cnt);
        scan_partial_kernel<<<NB, SCAN_BLOCK, 0, stream>>>(cnt, N, bsum);
        scan_bsums_kernel<<<1, 1024, 0, stream>>>(bsum, NB);
        scan_apply_kernel<<<NB, SCAN_BLOCK, 0, stream>>>(cnt, N, bsum, NB, ptr, isq);
        scatter_kernel<<<grid_for(stride2, 256), 256, 0, stream>>>(
            g.rows, g.cols, H, stride2, cnt, ci);

        // --- init: curS = isq.*concat(fA,fB); acc = concat/3 ---
        init_concat_kernel<<<grid_for((long long)N * (EMB / 4), 256), 256, 0, stream>>>(
            g.fA, g.fB, isq, g.nA, N, buf0, acc);

        // --- 2 layers of fused gather-SpMM + norm + accumulate ---
        float* cur = buf0;
        float* nxt = buf1;
        for (int layer = 0; layer < 2; ++layer) {
            int writeNext = (layer + 1 < 2) ? 1 : 0;
            spmm_norm_kernel<<<grid_for((long long)N * EMB, 256), 256, 0, stream>>>(
                ptr, ci, isq, cur, nxt, acc, N, writeNext);
            float* t = cur; cur = nxt; nxt = t;
        }
        out_off += (long long)N * EMB;
    }
}

// Round 7
// 2025.506 us; speedup vs baseline: 1.1928x; 1.1928x over previous
//
#include <hip/hip_runtime.h>
#include <hip/hip_bf16.h>

// LightGCN propagation, 3 bipartite graphs. Round 7: disjoint-UNION-graph
// fusion — all 3 graphs share one node index space (offsets 0 / N0 / N0+N1),
// one CSR, one acc (= d_out directly). Every phase is a single dispatch
// (9 total vs 24), tripling parallelism in the latency-bound hist/scatter.
// curS/nxtS stored as bf16 (fp32 accumulate) -> half gather bytes, half
// ping-pong workspace.
//  * rows = concat(r, c+nA), cols = concat(c+nA, r) per graph (mirrored) ->
//    read only first E/2 pairs, emit both directions.
//  * vals[e] = isq[rows[e]]*isq[cols[e]], deg = histogram -> value-free CSR.

constexpr int EMB = 64;
constexpr float THIRD = 1.0f / 3.0f;
constexpr float EPS_NRM = 1e-12f;
constexpr float EPS_LAP = 1e-8f;
constexpr int SCAN_BLOCK = 256;
constexpr int SCAN_ITEMS = 8;
constexpr int SCAN_TILE = SCAN_BLOCK * SCAN_ITEMS;  // 2048

__device__ __forceinline__ unsigned short f2b(float x) {
    __hip_bfloat16 h = __float2bfloat16(x);
    return *reinterpret_cast<unsigned short*>(&h);
}
__device__ __forceinline__ float b2f(unsigned short u) {
    return __uint_as_float(((unsigned)u) << 16);
}

// Union histogram: pair p -> graph by range, both endpoints +1.
__global__ void hist3_kernel(const int* __restrict__ r0, const int* __restrict__ c0,
                             const int* __restrict__ r1, const int* __restrict__ c1,
                             const int* __restrict__ r2, const int* __restrict__ c2,
                             long long H0, long long H01, long long H,
                             int off1, int off2,
                             int* __restrict__ cnt) {
    long long p = blockIdx.x * (long long)blockDim.x + threadIdx.x;
    if (p >= H) return;
    int a, b;
    if (p < H0)      { a = r0[p];                 b = c0[p]; }
    else if (p < H01){ long long i = p - H0;  a = r1[i] + off1; b = c1[i] + off1; }
    else             { long long i = p - H01; a = r2[i] + off2; b = c2[i] + off2; }
    atomicAdd(&cnt[a], 1);
    atomicAdd(&cnt[b], 1);
}

// --- two-level scan (over the union cnt array) ------------------------------
__global__ void scan_partial_kernel(const int* __restrict__ cnt, int N,
                                    int* __restrict__ bsum) {
    __shared__ int red[SCAN_BLOCK];
    const int b = blockIdx.x;
    const int t = threadIdx.x;
    const int base = b * SCAN_TILE + t * SCAN_ITEMS;
    int s = 0;
    if (base + SCAN_ITEMS <= N) {
        int4 a = ((const int4*)cnt)[(base >> 2) + 0];
        int4 c = ((const int4*)cnt)[(base >> 2) + 1];
        s = a.x + a.y + a.z + a.w + c.x + c.y + c.z + c.w;
    } else {
        for (int k = 0; k < SCAN_ITEMS; ++k)
            if (base + k < N) s += cnt[base + k];
    }
    red[t] = s;
    __syncthreads();
    for (int off = SCAN_BLOCK / 2; off > 0; off >>= 1) {
        if (t < off) red[t] += red[t + off];
        __syncthreads();
    }
    if (t == 0) bsum[b] = red[0];
}

__global__ void scan_bsums_kernel(int* __restrict__ bsum, int NB) {
    __shared__ int s[1024];
    const int t = threadIdx.x;
    int v = (t < NB) ? bsum[t] : 0;
    s[t] = v;
    __syncthreads();
    for (int off = 1; off < 1024; off <<= 1) {
        int x = (t >= off) ? s[t - off] : 0;
        __syncthreads();
        s[t] += x;
        __syncthreads();
    }
    if (t < NB) bsum[t] = s[t] - v;      // exclusive prefix
    if (t == 1023) bsum[NB] = s[1023];   // total
}

__global__ void scan_apply_kernel(int* __restrict__ cnt, int N,
                                  const int* __restrict__ bsum, int NB,
                                  int* __restrict__ ptr,
                                  float* __restrict__ isq) {
    __shared__ int tsum[SCAN_BLOCK];
    const int b = blockIdx.x;
    const int t = threadIdx.x;
    const int base = b * SCAN_TILE + t * SCAN_ITEMS;
    int v[SCAN_ITEMS];
    int s = 0;
    if (base + SCAN_ITEMS <= N) {
        int4 a = ((const int4*)cnt)[(base >> 2) + 0];
        int4 c = ((const int4*)cnt)[(base >> 2) + 1];
        v[0] = a.x; v[1] = a.y; v[2] = a.z; v[3] = a.w;
        v[4] = c.x; v[5] = c.y; v[6] = c.z; v[7] = c.w;
        s = v[0] + v[1] + v[2] + v[3] + v[4] + v[5] + v[6] + v[7];
    } else {
        for (int k = 0; k < SCAN_ITEMS; ++k) {
            v[k] = (base + k < N) ? cnt[base + k] : 0;
            s += v[k];
        }
    }
    tsum[t] = s;
    __syncthreads();
    for (int off = 1; off < SCAN_BLOCK; off <<= 1) {
        int x = (t >= off) ? tsum[t - off] : 0;
        __syncthreads();
        tsum[t] += x;
        __syncthreads();
    }
    int run = bsum[b] + tsum[t] - s;
    for (int k = 0; k < SCAN_ITEMS; ++k) {
        if (base + k < N) {
            ptr[base + k] = run;
            cnt[base + k] = run;         // scatter cursor
            isq[base + k] = 1.0f / (sqrtf((float)v[k]) + EPS_LAP);
            run += v[k];
        }
    }
    if (b == 0 && t == 0) ptr[N] = bsum[NB];
}
// ----------------------------------------------------------------------------

// Union scatter: 1 pair/thread, both directions (2 atomics + 2 scattered
// writes in flight), 5M threads total.
__global__ void scatter3_kernel(const int* __restrict__ r0, const int* __restrict__ c0,
                                const int* __restrict__ r1, const int* __restrict__ c1,
                                const int* __restrict__ r2, const int* __restrict__ c2,
                                long long H0, long long H01, long long H,
                                int off1, int off2,
                                int* __restrict__ cursor,
                                int* __restrict__ ci) {
    long long p = blockIdx.x * (long long)blockDim.x + threadIdx.x;
    if (p >= H) return;
    int a, b;
    if (p < H0)      { a = r0[p];                 b = c0[p]; }
    else if (p < H01){ long long i = p - H0;  a = r1[i] + off1; b = c1[i] + off1; }
    else             { long long i = p - H01; a = r2[i] + off2; b = c2[i] + off2; }
    int pa = atomicAdd(&cursor[a], 1);
    int pb = atomicAdd(&cursor[b], 1);
    ci[pa] = b;
    ci[pb] = a;
}

// Union init: node n -> (graph, A/B feature source). curS = bf16(isq*x);
// acc = x/3 (fp32, directly in d_out).
__global__ void init3_kernel(const float4* __restrict__ fu,
                             const float4* __restrict__ fb,
                             const float4* __restrict__ fi,
                             int nU, int nB, int nI,
                             int off1, int off2, int Ntot,
                             const float* __restrict__ isq,
                             ushort4* __restrict__ curS,
                             float4* __restrict__ acc) {
    long long total = (long long)Ntot * 16;
    long long i = blockIdx.x * (long long)blockDim.x + threadIdx.x;
    if (i >= total) return;
    int n = (int)(i >> 4);
    int ch = (int)(i & 15);
    float4 v;
    if (n < off1) {
        v = (n < nU) ? fu[(long long)n * 16 + ch]
                     : fb[(long long)(n - nU) * 16 + ch];
    } else if (n < off2) {
        int l = n - off1;
        v = (l < nU) ? fu[(long long)l * 16 + ch]
                     : fi[(long long)(l - nU) * 16 + ch];
    } else {
        int l = n - off2;
        v = (l < nB) ? fb[(long long)l * 16 + ch]
                     : fi[(long long)(l - nB) * 16 + ch];
    }
    float q = isq[n];
    curS[i] = make_ushort4(f2b(v.x * q), f2b(v.y * q), f2b(v.z * q), f2b(v.w * q));
    acc[i] = make_float4(v.x * THIRD, v.y * THIRD, v.z * THIRD, v.w * THIRD);
}

// One wave per union row; lane owns one dim. bf16 gathers (fp32 accumulate),
// 4-way unrolled; fused row-L2-norm + acc update; optional bf16 nxtS write.
__global__ void spmm_norm_kernel(const int* __restrict__ ptr,
                                 const int* __restrict__ ci,
                                 const float* __restrict__ isq,
                                 const unsigned short* __restrict__ curS,
                                 unsigned short* __restrict__ nxtS,
                                 float* __restrict__ acc,
                                 int N, int writeNext) {
    int gid = (int)((blockIdx.x * (long long)blockDim.x + threadIdx.x) >> 6);
    int lane = threadIdx.x & 63;
    if (gid >= N) return;
    const int beg = ptr[gid];
    const int end = ptr[gid + 1];
    float s = 0.0f;
    int j = beg;
    for (; j + 4 <= end; j += 4) {
        int c0 = ci[j];
        int c1 = ci[j + 1];
        int c2 = ci[j + 2];
        int c3 = ci[j + 3];
        float g0 = b2f(curS[(long long)c0 * EMB + lane]);
        float g1 = b2f(curS[(long long)c1 * EMB + lane]);
        float g2 = b2f(curS[(long long)c2 * EMB + lane]);
        float g3 = b2f(curS[(long long)c3 * EMB + lane]);
        s += g0 + g1 + g2 + g3;
    }
    for (; j < end; ++j) {
        s += b2f(curS[(long long)ci[j] * EMB + lane]);
    }
    const float q = isq[gid];
    float raw = s * q;
    float ss = raw * raw;
    ss += __shfl_xor(ss, 1, 64);
    ss += __shfl_xor(ss, 2, 64);
    ss += __shfl_xor(ss, 4, 64);
    ss += __shfl_xor(ss, 8, 64);
    ss += __shfl_xor(ss, 16, 64);
    ss += __shfl_xor(ss, 32, 64);
    const long long idx = (long long)gid * EMB + lane;
    if (writeNext) nxtS[idx] = f2b(raw * q);
    float scale = THIRD / fmaxf(sqrtf(ss), EPS_NRM);
    acc[idx] += raw * scale;
}

static inline int grid_for(long long total, int block) {
    long long g = (total + block - 1) / block;
    if (g > (1LL << 20)) g = (1LL << 20);
    if (g < 1) g = 1;
    return (int)g;
}

extern "C" void kernel_launch(void* const* d_in, const int* in_sizes, int n_in,
                              void* d_out, int out_size, void* d_ws, size_t ws_size,
                              hipStream_t stream) {
    const float* fu = (const float*)d_in[0];
    const float* fb = (const float*)d_in[1];
    const float* fi = (const float*)d_in[2];
    const int nU = in_sizes[0] / EMB;
    const int nB = in_sizes[1] / EMB;
    const int nI = in_sizes[2] / EMB;
    float* out = (float*)d_out;

    // Union-graph geometry.
    const int N0 = nU + nB, N1 = nU + nI, N2 = nB + nI;
    const int off1 = N0;
    const int off2 = N0 + N1;
    const int Ntot = N0 + N1 + N2;
    const long long H0 = (long long)in_sizes[3] / 2;
    const long long H1 = (long long)in_sizes[6] / 2;
    const long long H2 = (long long)in_sizes[9] / 2;
    const long long H01 = H0 + H1;
    const long long H = H0 + H1 + H2;
    const long long Etot = 2 * H;
    const int NB_ = (Ntot + SCAN_TILE - 1) / SCAN_TILE;

    const int* r0 = (const int*)d_in[3];
    const int* c0 = (const int*)d_in[4];
    const int* r1 = (const int*)d_in[6];
    const int* c1 = (const int*)d_in[7];
    const int* r2 = (const int*)d_in[9];
    const int* c2 = (const int*)d_in[10];

    // Workspace layout (16B-aligned chunks):
    //   curS0/curS1: Ntot*64 bf16 each (ping-pong, 43.5MB each)
    //   ptr/cnt:     Ntot+pad ints; isq: Ntot+pad floats; bsum: NB+pad ints
    //   ci:          Etot ints (40MB)
    char* w = (char*)d_ws;
    unsigned short* bufA = (unsigned short*)w;  w += (size_t)Ntot * EMB * sizeof(unsigned short);
    unsigned short* bufB = (unsigned short*)w;  w += (size_t)Ntot * EMB * sizeof(unsigned short);
    int* ptr = (int*)w;                         w += (size_t)((Ntot + 8) & ~7) * sizeof(int);
    int* cnt = (int*)w;                         w += (size_t)((Ntot + 8) & ~7) * sizeof(int);
    float* isq = (float*)w;                     w += (size_t)((Ntot + 8) & ~7) * sizeof(float);
    int* bsum = (int*)w;                        w += (size_t)((NB_ + 8) & ~7) * sizeof(int);
    int* ci = (int*)w;

    // --- CSR build over the union graph (one dispatch per phase) ---
    hipMemsetAsync(cnt, 0, (size_t)Ntot * sizeof(int), stream);
    hist3_kernel<<<grid_for(H, 256), 256, 0, stream>>>(
        r0, c0, r1, c1, r2, c2, H0, H01, H, off1, off2, cnt);
    scan_partial_kernel<<<NB_, SCAN_BLOCK, 0, stream>>>(cnt, Ntot, bsum);
    scan_bsums_kernel<<<1, 1024, 0, stream>>>(bsum, NB_);
    scan_apply_kernel<<<NB_, SCAN_BLOCK, 0, stream>>>(cnt, Ntot, bsum, NB_, ptr, isq);
    scatter3_kernel<<<grid_for(H, 256), 256, 0, stream>>>(
        r0, c0, r1, c1, r2, c2, H0, H01, H, off1, off2, cnt, ci);

    // --- init: curS = bf16(isq.*x); acc = x/3 (into d_out) ---
    init3_kernel<<<grid_for((long long)Ntot * 16, 256), 256, 0, stream>>>(
        (const float4*)fu, (const float4*)fb, (const float4*)fi,
        nU, nB, nI, off1, off2, Ntot, isq, (ushort4*)bufA, (float4*)out);

    // --- 2 fused layers over the whole union ---
    unsigned short* cur = bufA;
    unsigned short* nxt = bufB;
    for (int layer = 0; layer < 2; ++layer) {
        int writeNext = (layer + 1 < 2) ? 1 : 0;
        spmm_norm_kernel<<<grid_for((long long)Ntot * EMB, 256), 256, 0, stream>>>(
            ptr, ci, isq, cur, nxt, out, Ntot, writeNext);
        unsigned short* t = cur; cur = nxt; nxt = t;
    }
}

// Round 8
// 1923.247 us; speedup vs baseline: 1.2563x; 1.0532x over previous
//
#include <hip/hip_runtime.h>
#include <hip/hip_bf16.h>

// LightGCN propagation, 3 bipartite graphs. Round 8: max-thread scatter.
// Evidence (r3/r6/r7): scatter throughput scales with THREAD count, not
// ops/thread — the memory-side fetch-add latency is hidden by wave-level
// parallelism. So: 1 thread per DIRECTED edge (2H = 10M threads), each
// 1 atomic + 1 store (hist: 1 atomic). Union-graph structure + bf16
// features kept from round 7.

constexpr int EMB = 64;
constexpr float THIRD = 1.0f / 3.0f;
constexpr float EPS_NRM = 1e-12f;
constexpr float EPS_LAP = 1e-8f;
constexpr int SCAN_BLOCK = 256;
constexpr int SCAN_ITEMS = 8;
constexpr int SCAN_TILE = SCAN_BLOCK * SCAN_ITEMS;  // 2048

__device__ __forceinline__ unsigned short f2b(float x) {
    __hip_bfloat16 h = __float2bfloat16(x);
    return *reinterpret_cast<unsigned short*>(&h);
}
__device__ __forceinline__ float b2f(unsigned short u) {
    return __uint_as_float(((unsigned)u) << 16);
}

// 1 thread per directed edge; histogram = count of each edge's source node.
// Directed edge t<H is (a->b): row a; t>=H is (b->a): row b.
__global__ void hist3_kernel(const int* __restrict__ r0, const int* __restrict__ c0,
                             const int* __restrict__ r1, const int* __restrict__ c1,
                             const int* __restrict__ r2, const int* __restrict__ c2,
                             long long H0, long long H01, long long H,
                             int off1, int off2,
                             int* __restrict__ cnt) {
    long long t = blockIdx.x * (long long)blockDim.x + threadIdx.x;
    if (t >= 2 * H) return;
    const bool second = (t >= H);
    long long p = second ? t - H : t;
    int node;
    if (p < H0)       { node = second ? c0[p] : r0[p]; }
    else if (p < H01) { long long i = p - H0;  node = (second ? c1[i] : r1[i]) + off1; }
    else              { long long i = p - H01; node = (second ? c2[i] : r2[i]) + off2; }
    atomicAdd(&cnt[node], 1);
}

// --- two-level scan (over the union cnt array) ------------------------------
__global__ void scan_partial_kernel(const int* __restrict__ cnt, int N,
                                    int* __restrict__ bsum) {
    __shared__ int red[SCAN_BLOCK];
    const int b = blockIdx.x;
    const int t = threadIdx.x;
    const int base = b * SCAN_TILE + t * SCAN_ITEMS;
    int s = 0;
    if (base + SCAN_ITEMS <= N) {
        int4 a = ((const int4*)cnt)[(base >> 2) + 0];
        int4 c = ((const int4*)cnt)[(base >> 2) + 1];
        s = a.x + a.y + a.z + a.w + c.x + c.y + c.z + c.w;
    } else {
        for (int k = 0; k < SCAN_ITEMS; ++k)
            if (base + k < N) s += cnt[base + k];
    }
    red[t] = s;
    __syncthreads();
    for (int off = SCAN_BLOCK / 2; off > 0; off >>= 1) {
        if (t < off) red[t] += red[t + off];
        __syncthreads();
    }
    if (t == 0) bsum[b] = red[0];
}

__global__ void scan_bsums_kernel(int* __restrict__ bsum, int NB) {
    __shared__ int s[1024];
    const int t = threadIdx.x;
    int v = (t < NB) ? bsum[t] : 0;
    s[t] = v;
    __syncthreads();
    for (int off = 1; off < 1024; off <<= 1) {
        int x = (t >= off) ? s[t - off] : 0;
        __syncthreads();
        s[t] += x;
        __syncthreads();
    }
    if (t < NB) bsum[t] = s[t] - v;      // exclusive prefix
    if (t == 1023) bsum[NB] = s[1023];   // total
}

__global__ void scan_apply_kernel(int* __restrict__ cnt, int N,
                                  const int* __restrict__ bsum, int NB,
                                  int* __restrict__ ptr,
                                  float* __restrict__ isq) {
    __shared__ int tsum[SCAN_BLOCK];
    const int b = blockIdx.x;
    const int t = threadIdx.x;
    const int base = b * SCAN_TILE + t * SCAN_ITEMS;
    int v[SCAN_ITEMS];
    int s = 0;
    if (base + SCAN_ITEMS <= N) {
        int4 a = ((const int4*)cnt)[(base >> 2) + 0];
        int4 c = ((const int4*)cnt)[(base >> 2) + 1];
        v[0] = a.x; v[1] = a.y; v[2] = a.z; v[3] = a.w;
        v[4] = c.x; v[5] = c.y; v[6] = c.z; v[7] = c.w;
        s = v[0] + v[1] + v[2] + v[3] + v[4] + v[5] + v[6] + v[7];
    } else {
        for (int k = 0; k < SCAN_ITEMS; ++k) {
            v[k] = (base + k < N) ? cnt[base + k] : 0;
            s += v[k];
        }
    }
    tsum[t] = s;
    __syncthreads();
    for (int off = 1; off < SCAN_BLOCK; off <<= 1) {
        int x = (t >= off) ? tsum[t - off] : 0;
        __syncthreads();
        tsum[t] += x;
        __syncthreads();
    }
    int run = bsum[b] + tsum[t] - s;
    for (int k = 0; k < SCAN_ITEMS; ++k) {
        if (base + k < N) {
            ptr[base + k] = run;
            cnt[base + k] = run;         // scatter cursor
            isq[base + k] = 1.0f / (sqrtf((float)v[k]) + EPS_LAP);
            run += v[k];
        }
    }
    if (b == 0 && t == 0) ptr[N] = bsum[NB];
}
// ----------------------------------------------------------------------------

// 1 thread per directed edge: 1 fetch-add + 1 scattered store.
__global__ void scatter3_kernel(const int* __restrict__ r0, const int* __restrict__ c0,
                                const int* __restrict__ r1, const int* __restrict__ c1,
                                const int* __restrict__ r2, const int* __restrict__ c2,
                                long long H0, long long H01, long long H,
                                int off1, int off2,
                                int* __restrict__ cursor,
                                int* __restrict__ ci) {
    long long t = blockIdx.x * (long long)blockDim.x + threadIdx.x;
    if (t >= 2 * H) return;
    const bool second = (t >= H);
    long long p = second ? t - H : t;
    int a, b;
    if (p < H0)       { a = r0[p];                  b = c0[p]; }
    else if (p < H01) { long long i = p - H0;  a = r1[i] + off1; b = c1[i] + off1; }
    else              { long long i = p - H01; a = r2[i] + off2; b = c2[i] + off2; }
    int row = second ? b : a;
    int col = second ? a : b;
    int pos = atomicAdd(&cursor[row], 1);
    ci[pos] = col;
}

// Union init: node n -> (graph, A/B feature source). curS = bf16(isq*x);
// acc = x/3 (fp32, directly in d_out).
__global__ void init3_kernel(const float4* __restrict__ fu,
                             const float4* __restrict__ fb,
                             const float4* __restrict__ fi,
                             int nU, int nB, int nI,
                             int off1, int off2, int Ntot,
                             const float* __restrict__ isq,
                             ushort4* __restrict__ curS,
                             float4* __restrict__ acc) {
    long long total = (long long)Ntot * 16;
    long long i = blockIdx.x * (long long)blockDim.x + threadIdx.x;
    if (i >= total) return;
    int n = (int)(i >> 4);
    int ch = (int)(i & 15);
    float4 v;
    if (n < off1) {
        v = (n < nU) ? fu[(long long)n * 16 + ch]
                     : fb[(long long)(n - nU) * 16 + ch];
    } else if (n < off2) {
        int l = n - off1;
        v = (l < nU) ? fu[(long long)l * 16 + ch]
                     : fi[(long long)(l - nU) * 16 + ch];
    } else {
        int l = n - off2;
        v = (l < nB) ? fb[(long long)l * 16 + ch]
                     : fi[(long long)(l - nB) * 16 + ch];
    }
    float q = isq[n];
    curS[i] = make_ushort4(f2b(v.x * q), f2b(v.y * q), f2b(v.z * q), f2b(v.w * q));
    acc[i] = make_float4(v.x * THIRD, v.y * THIRD, v.z * THIRD, v.w * THIRD);
}

// One wave per union row; lane owns one dim. bf16 gathers (fp32 accumulate),
// 4-way unrolled; fused row-L2-norm + acc update; optional bf16 nxtS write.
__global__ void spmm_norm_kernel(const int* __restrict__ ptr,
                                 const int* __restrict__ ci,
                                 const float* __restrict__ isq,
                                 const unsigned short* __restrict__ curS,
                                 unsigned short* __restrict__ nxtS,
                                 float* __restrict__ acc,
                                 int N, int writeNext) {
    int gid = (int)((blockIdx.x * (long long)blockDim.x + threadIdx.x) >> 6);
    int lane = threadIdx.x & 63;
    if (gid >= N) return;
    const int beg = ptr[gid];
    const int end = ptr[gid + 1];
    float s = 0.0f;
    int j = beg;
    for (; j + 4 <= end; j += 4) {
        int c0 = ci[j];
        int c1 = ci[j + 1];
        int c2 = ci[j + 2];
        int c3 = ci[j + 3];
        float g0 = b2f(curS[(long long)c0 * EMB + lane]);
        float g1 = b2f(curS[(long long)c1 * EMB + lane]);
        float g2 = b2f(curS[(long long)c2 * EMB + lane]);
        float g3 = b2f(curS[(long long)c3 * EMB + lane]);
        s += g0 + g1 + g2 + g3;
    }
    for (; j < end; ++j) {
        s += b2f(curS[(long long)ci[j] * EMB + lane]);
    }
    const float q = isq[gid];
    float raw = s * q;
    float ss = raw * raw;
    ss += __shfl_xor(ss, 1, 64);
    ss += __shfl_xor(ss, 2, 64);
    ss += __shfl_xor(ss, 4, 64);
    ss += __shfl_xor(ss, 8, 64);
    ss += __shfl_xor(ss, 16, 64);
    ss += __shfl_xor(ss, 32, 64);
    const long long idx = (long long)gid * EMB + lane;
    if (writeNext) nxtS[idx] = f2b(raw * q);
    float scale = THIRD / fmaxf(sqrtf(ss), EPS_NRM);
    acc[idx] += raw * scale;
}

static inline int grid_for(long long total, int block) {
    long long g = (total + block - 1) / block;
    if (g > (1LL << 20)) g = (1LL << 20);
    if (g < 1) g = 1;
    return (int)g;
}

extern "C" void kernel_launch(void* const* d_in, const int* in_sizes, int n_in,
                              void* d_out, int out_size, void* d_ws, size_t ws_size,
                              hipStream_t stream) {
    const float* fu = (const float*)d_in[0];
    const float* fb = (const float*)d_in[1];
    const float* fi = (const float*)d_in[2];
    const int nU = in_sizes[0] / EMB;
    const int nB = in_sizes[1] / EMB;
    const int nI = in_sizes[2] / EMB;
    float* out = (float*)d_out;

    // Union-graph geometry.
    const int N0 = nU + nB, N1 = nU + nI, N2 = nB + nI;
    const int off1 = N0;
    const int off2 = N0 + N1;
    const int Ntot = N0 + N1 + N2;
    const long long H0 = (long long)in_sizes[3] / 2;
    const long long H1 = (long long)in_sizes[6] / 2;
    const long long H2 = (long long)in_sizes[9] / 2;
    const long long H01 = H0 + H1;
    const long long H = H0 + H1 + H2;
    const int NB_ = (Ntot + SCAN_TILE - 1) / SCAN_TILE;

    const int* r0 = (const int*)d_in[3];
    const int* c0 = (const int*)d_in[4];
    const int* r1 = (const int*)d_in[6];
    const int* c1 = (const int*)d_in[7];
    const int* r2 = (const int*)d_in[9];
    const int* c2 = (const int*)d_in[10];

    // Workspace layout (16B-aligned chunks):
    char* w = (char*)d_ws;
    unsigned short* bufA = (unsigned short*)w;  w += (size_t)Ntot * EMB * sizeof(unsigned short);
    unsigned short* bufB = (unsigned short*)w;  w += (size_t)Ntot * EMB * sizeof(unsigned short);
    int* ptr = (int*)w;                         w += (size_t)((Ntot + 8) & ~7) * sizeof(int);
    int* cnt = (int*)w;                         w += (size_t)((Ntot + 8) & ~7) * sizeof(int);
    float* isq = (float*)w;                     w += (size_t)((Ntot + 8) & ~7) * sizeof(float);
    int* bsum = (int*)w;                        w += (size_t)((NB_ + 8) & ~7) * sizeof(int);
    int* ci = (int*)w;

    // --- CSR build over the union graph ---
    hipMemsetAsync(cnt, 0, (size_t)Ntot * sizeof(int), stream);
    hist3_kernel<<<grid_for(2 * H, 256), 256, 0, stream>>>(
        r0, c0, r1, c1, r2, c2, H0, H01, H, off1, off2, cnt);
    scan_partial_kernel<<<NB_, SCAN_BLOCK, 0, stream>>>(cnt, Ntot, bsum);
    scan_bsums_kernel<<<1, 1024, 0, stream>>>(bsum, NB_);
    scan_apply_kernel<<<NB_, SCAN_BLOCK, 0, stream>>>(cnt, Ntot, bsum, NB_, ptr, isq);
    scatter3_kernel<<<grid_for(2 * H, 256), 256, 0, stream>>>(
        r0, c0, r1, c1, r2, c2, H0, H01, H, off1, off2, cnt, ci);

    // --- init: curS = bf16(isq.*x); acc = x/3 (into d_out) ---
    init3_kernel<<<grid_for((long long)Ntot * 16, 256), 256, 0, stream>>>(
        (const float4*)fu, (const float4*)fb, (const float4*)fi,
        nU, nB, nI, off1, off2, Ntot, isq, (ushort4*)bufA, (float4*)out);

    // --- 2 fused layers over the whole union ---
    unsigned short* cur = bufA;
    unsigned short* nxt = bufB;
    for (int layer = 0; layer < 2; ++layer) {
        int writeNext = (layer + 1 < 2) ? 1 : 0;
        spmm_norm_kernel<<<grid_for((long long)Ntot * EMB, 256), 256, 0, stream>>>(
            ptr, ci, isq, cur, nxt, out, Ntot, writeNext);
        unsigned short* t = cur; cur = nxt; nxt = t;
    }
}

// Round 9
// 1907.621 us; speedup vs baseline: 1.2666x; 1.0082x over previous
//
#include <hip/hip_runtime.h>
#include <hip/hip_bf16.h>

// LightGCN propagation, 3 bipartite graphs. Round 9: XCD-local CSR atomics.
// Evidence (r1 vs r8): fire-and-forget atomics run ~75G/s, but the scatter's
// fetch-add NEEDS its return -> device-scope round-trip to memory-side
// (per-XCD L2s non-coherent) stalls every edge ~600-900cy. Fix: per-(node,
// XCD) counters/cursors indexed node*8+XCC_ID, so each counter is touched by
// ONE die only -> workgroup-scope atomic = L2-local RMW (8 L2s in parallel,
// ~4x lower latency). Scan over node-major/xcc-minor counters yields an
// EXACT CSR with per-row-contiguous ci (no padding); spmm reads
// ptr8[n*8]..ptr8[n*8+8]. Union-graph + bf16 features kept from r7/r8.

constexpr int EMB = 64;
constexpr int NXCD = 8;
constexpr float THIRD = 1.0f / 3.0f;
constexpr float EPS_NRM = 1e-12f;
constexpr float EPS_LAP = 1e-8f;
constexpr int SCAN_BLOCK = 256;
constexpr int SCAN_ITEMS = 16;       // = 2 nodes' worth of (node,xcd) counters
constexpr int SCAN_TILE = SCAN_BLOCK * SCAN_ITEMS;  // 4096

__device__ __forceinline__ unsigned short f2b(float x) {
    __hip_bfloat16 h = __float2bfloat16(x);
    return *reinterpret_cast<unsigned short*>(&h);
}
__device__ __forceinline__ float b2f(unsigned short u) {
    return __uint_as_float(((unsigned)u) << 16);
}
__device__ __forceinline__ int xcc_id() {
    unsigned x;
    asm volatile("s_getreg_b32 %0, hwreg(HW_REG_XCC_ID)" : "=s"(x));
    return (int)(x & (NXCD - 1));
}
__device__ __forceinline__ int fadd_local(int* p) {
    return __hip_atomic_fetch_add(p, 1, __ATOMIC_RELAXED,
                                  __HIP_MEMORY_SCOPE_WORKGROUP);
}

// 1 thread per directed edge; bump cnt8[node*8 + xcc] (L2-local, no return).
__global__ void hist3_kernel(const int* __restrict__ r0, const int* __restrict__ c0,
                             const int* __restrict__ r1, const int* __restrict__ c1,
                             const int* __restrict__ r2, const int* __restrict__ c2,
                             long long H0, long long H01, long long H,
                             int off1, int off2,
                             int* __restrict__ cnt) {
    long long t = blockIdx.x * (long long)blockDim.x + threadIdx.x;
    if (t >= 2 * H) return;
    const bool second = (t >= H);
    long long p = second ? t - H : t;
    int node;
    if (p < H0)       { node = second ? c0[p] : r0[p]; }
    else if (p < H01) { long long i = p - H0;  node = (second ? c1[i] : r1[i]) + off1; }
    else              { long long i = p - H01; node = (second ? c2[i] : r2[i]) + off2; }
    (void)fadd_local(&cnt[(long long)node * NXCD + xcc_id()]);
}

// --- two-level scan over N8 = Ntot*8 (node,xcd) counters --------------------
__global__ void scan_partial_kernel(const int* __restrict__ cnt, int N8,
                                    int* __restrict__ bsum) {
    __shared__ int red[SCAN_BLOCK];
    const int b = blockIdx.x;
    const int t = threadIdx.x;
    const int base = b * SCAN_TILE + t * SCAN_ITEMS;
    int s = 0;
    if (base + SCAN_ITEMS <= N8) {
        #pragma unroll
        for (int q = 0; q < 4; ++q) {
            int4 a = ((const int4*)cnt)[(base >> 2) + q];
            s += a.x + a.y + a.z + a.w;
        }
    } else {
        for (int k = 0; k < SCAN_ITEMS; ++k)
            if (base + k < N8) s += cnt[base + k];
    }
    red[t] = s;
    __syncthreads();
    for (int off = SCAN_BLOCK / 2; off > 0; off >>= 1) {
        if (t < off) red[t] += red[t + off];
        __syncthreads();
    }
    if (t == 0) bsum[b] = red[0];
}

__global__ void scan_bsums_kernel(int* __restrict__ bsum, int NB) {
    __shared__ int s[1024];
    const int t = threadIdx.x;
    int v = (t < NB) ? bsum[t] : 0;
    s[t] = v;
    __syncthreads();
    for (int off = 1; off < 1024; off <<= 1) {
        int x = (t >= off) ? s[t - off] : 0;
        __syncthreads();
        s[t] += x;
        __syncthreads();
    }
    if (t < NB) bsum[t] = s[t] - v;      // exclusive prefix
    if (t == 1023) bsum[NB] = s[1023];   // total
}

// Exclusive scan + cursor init; each thread owns exactly 2 nodes (16
// counters), so per-node degree = local 8-sum -> isq computed here.
__global__ void scan_apply_kernel(int* __restrict__ cnt, int N8,
                                  const int* __restrict__ bsum, int NB,
                                  int* __restrict__ ptr,
                                  float* __restrict__ isq) {
    __shared__ int tsum[SCAN_BLOCK];
    const int b = blockIdx.x;
    const int t = threadIdx.x;
    const int base = b * SCAN_TILE + t * SCAN_ITEMS;
    int v[SCAN_ITEMS];
    int s = 0;
    if (base + SCAN_ITEMS <= N8) {
        #pragma unroll
        for (int q = 0; q < 4; ++q) {
            int4 a = ((const int4*)cnt)[(base >> 2) + q];
            v[4 * q + 0] = a.x; v[4 * q + 1] = a.y;
            v[4 * q + 2] = a.z; v[4 * q + 3] = a.w;
        }
        #pragma unroll
        for (int k = 0; k < SCAN_ITEMS; ++k) s += v[k];
    } else {
        for (int k = 0; k < SCAN_ITEMS; ++k) {
            v[k] = (base + k < N8) ? cnt[base + k] : 0;
            s += v[k];
        }
    }
    tsum[t] = s;
    __syncthreads();
    for (int off = 1; off < SCAN_BLOCK; off <<= 1) {
        int x = (t >= off) ? tsum[t - off] : 0;
        __syncthreads();
        tsum[t] += x;
        __syncthreads();
    }
    int run = bsum[b] + tsum[t] - s;
    for (int k = 0; k < SCAN_ITEMS; ++k) {
        if (base + k < N8) {
            ptr[base + k] = run;
            cnt[base + k] = run;         // scatter cursor
            run += v[k];
        }
    }
    // base is a multiple of 16 and N8 a multiple of 8 -> full-node chunks.
    if (base < N8) {
        int d0 = v[0] + v[1] + v[2] + v[3] + v[4] + v[5] + v[6] + v[7];
        isq[base >> 3] = 1.0f / (sqrtf((float)d0) + EPS_LAP);
    }
    if (base + 8 < N8) {
        int d1 = v[8] + v[9] + v[10] + v[11] + v[12] + v[13] + v[14] + v[15];
        isq[(base >> 3) + 1] = 1.0f / (sqrtf((float)d1) + EPS_LAP);
    }
    if (b == 0 && t == 0) ptr[N8] = bsum[NB];
}
// ----------------------------------------------------------------------------

// 1 thread per directed edge: L2-local fetch-add on the (row,xcc) cursor +
// 1 scattered store. Positions are globally unique and row-contiguous.
__global__ void scatter3_kernel(const int* __restrict__ r0, const int* __restrict__ c0,
                                const int* __restrict__ r1, const int* __restrict__ c1,
                                const int* __restrict__ r2, const int* __restrict__ c2,
                                long long H0, long long H01, long long H,
                                int off1, int off2,
                                int* __restrict__ cursor,
                                int* __restrict__ ci) {
    long long t = blockIdx.x * (long long)blockDim.x + threadIdx.x;
    if (t >= 2 * H) return;
    const bool second = (t >= H);
    long long p = second ? t - H : t;
    int a, b;
    if (p < H0)       { a = r0[p];                  b = c0[p]; }
    else if (p < H01) { long long i = p - H0;  a = r1[i] + off1; b = c1[i] + off1; }
    else              { long long i = p - H01; a = r2[i] + off2; b = c2[i] + off2; }
    int row = second ? b : a;
    int col = second ? a : b;
    int pos = fadd_local(&cursor[(long long)row * NXCD + xcc_id()]);
    ci[pos] = col;
}

// Union init: node n -> (graph, A/B feature source). curS = bf16(isq*x);
// acc = x/3 (fp32, directly in d_out).
__global__ void init3_kernel(const float4* __restrict__ fu,
                             const float4* __restrict__ fb,
                             const float4* __restrict__ fi,
                             int nU, int nB, int nI,
                             int off1, int off2, int Ntot,
                             const float* __restrict__ isq,
                             ushort4* __restrict__ curS,
                             float4* __restrict__ acc) {
    long long total = (long long)Ntot * 16;
    long long i = blockIdx.x * (long long)blockDim.x + threadIdx.x;
    if (i >= total) return;
    int n = (int)(i >> 4);
    int ch = (int)(i & 15);
    float4 v;
    if (n < off1) {
        v = (n < nU) ? fu[(long long)n * 16 + ch]
                     : fb[(long long)(n - nU) * 16 + ch];
    } else if (n < off2) {
        int l = n - off1;
        v = (l < nU) ? fu[(long long)l * 16 + ch]
                     : fi[(long long)(l - nU) * 16 + ch];
    } else {
        int l = n - off2;
        v = (l < nB) ? fb[(long long)l * 16 + ch]
                     : fi[(long long)(l - nB) * 16 + ch];
    }
    float q = isq[n];
    curS[i] = make_ushort4(f2b(v.x * q), f2b(v.y * q), f2b(v.z * q), f2b(v.w * q));
    acc[i] = make_float4(v.x * THIRD, v.y * THIRD, v.z * THIRD, v.w * THIRD);
}

// One wave per union row; lane owns one dim. bf16 gathers (fp32 accumulate),
// 4-way unrolled; fused row-L2-norm + acc update; optional bf16 nxtS write.
// Row range: ptr8[n*8] .. ptr8[n*8+8].
__global__ void spmm_norm_kernel(const int* __restrict__ ptr8,
                                 const int* __restrict__ ci,
                                 const float* __restrict__ isq,
                                 const unsigned short* __restrict__ curS,
                                 unsigned short* __restrict__ nxtS,
                                 float* __restrict__ acc,
                                 int N, int writeNext) {
    int gid = (int)((blockIdx.x * (long long)blockDim.x + threadIdx.x) >> 6);
    int lane = threadIdx.x & 63;
    if (gid >= N) return;
    const int beg = ptr8[(long long)gid * NXCD];
    const int end = ptr8[(long long)gid * NXCD + NXCD];
    float s = 0.0f;
    int j = beg;
    for (; j + 4 <= end; j += 4) {
        int c0 = ci[j];
        int c1 = ci[j + 1];
        int c2 = ci[j + 2];
        int c3 = ci[j + 3];
        float g0 = b2f(curS[(long long)c0 * EMB + lane]);
        float g1 = b2f(curS[(long long)c1 * EMB + lane]);
        float g2 = b2f(curS[(long long)c2 * EMB + lane]);
        float g3 = b2f(curS[(long long)c3 * EMB + lane]);
        s += g0 + g1 + g2 + g3;
    }
    for (; j < end; ++j) {
        s += b2f(curS[(long long)ci[j] * EMB + lane]);
    }
    const float q = isq[gid];
    float raw = s * q;
    float ss = raw * raw;
    ss += __shfl_xor(ss, 1, 64);
    ss += __shfl_xor(ss, 2, 64);
    ss += __shfl_xor(ss, 4, 64);
    ss += __shfl_xor(ss, 8, 64);
    ss += __shfl_xor(ss, 16, 64);
    ss += __shfl_xor(ss, 32, 64);
    const long long idx = (long long)gid * EMB + lane;
    if (writeNext) nxtS[idx] = f2b(raw * q);
    float scale = THIRD / fmaxf(sqrtf(ss), EPS_NRM);
    acc[idx] += raw * scale;
}

static inline int grid_for(long long total, int block) {
    long long g = (total + block - 1) / block;
    if (g > (1LL << 20)) g = (1LL << 20);
    if (g < 1) g = 1;
    return (int)g;
}

extern "C" void kernel_launch(void* const* d_in, const int* in_sizes, int n_in,
                              void* d_out, int out_size, void* d_ws, size_t ws_size,
                              hipStream_t stream) {
    const float* fu = (const float*)d_in[0];
    const float* fb = (const float*)d_in[1];
    const float* fi = (const float*)d_in[2];
    const int nU = in_sizes[0] / EMB;
    const int nB = in_sizes[1] / EMB;
    const int nI = in_sizes[2] / EMB;
    float* out = (float*)d_out;

    // Union-graph geometry.
    const int N0 = nU + nB, N1 = nU + nI, N2 = nB + nI;
    const int off1 = N0;
    const int off2 = N0 + N1;
    const int Ntot = N0 + N1 + N2;
    const int N8 = Ntot * NXCD;
    const long long H0 = (long long)in_sizes[3] / 2;
    const long long H1 = (long long)in_sizes[6] / 2;
    const long long H2 = (long long)in_sizes[9] / 2;
    const long long H01 = H0 + H1;
    const long long H = H0 + H1 + H2;
    const int NB_ = (N8 + SCAN_TILE - 1) / SCAN_TILE;

    const int* r0 = (const int*)d_in[3];
    const int* c0 = (const int*)d_in[4];
    const int* r1 = (const int*)d_in[6];
    const int* c1 = (const int*)d_in[7];
    const int* r2 = (const int*)d_in[9];
    const int* c2 = (const int*)d_in[10];

    // Workspace layout (16B-aligned chunks): ~151MB total.
    char* w = (char*)d_ws;
    unsigned short* bufA = (unsigned short*)w;  w += (size_t)Ntot * EMB * sizeof(unsigned short);
    unsigned short* bufB = (unsigned short*)w;  w += (size_t)Ntot * EMB * sizeof(unsigned short);
    int* ptr8 = (int*)w;                        w += (size_t)(N8 + 16) * sizeof(int);
    int* cnt8 = (int*)w;                        w += (size_t)(N8 + 16) * sizeof(int);
    float* isq = (float*)w;                     w += (size_t)((Ntot + 8) & ~7) * sizeof(float);
    int* bsum = (int*)w;                        w += (size_t)((NB_ + 8) & ~7) * sizeof(int);
    int* ci = (int*)w;

    // --- CSR build over the union graph (XCD-local atomics) ---
    hipMemsetAsync(cnt8, 0, (size_t)N8 * sizeof(int), stream);
    hist3_kernel<<<grid_for(2 * H, 256), 256, 0, stream>>>(
        r0, c0, r1, c1, r2, c2, H0, H01, H, off1, off2, cnt8);
    scan_partial_kernel<<<NB_, SCAN_BLOCK, 0, stream>>>(cnt8, N8, bsum);
    scan_bsums_kernel<<<1, 1024, 0, stream>>>(bsum, NB_);
    scan_apply_kernel<<<NB_, SCAN_BLOCK, 0, stream>>>(cnt8, N8, bsum, NB_, ptr8, isq);
    scatter3_kernel<<<grid_for(2 * H, 256), 256, 0, stream>>>(
        r0, c0, r1, c1, r2, c2, H0, H01, H, off1, off2, cnt8, ci);

    // --- init: curS = bf16(isq.*x); acc = x/3 (into d_out) ---
    init3_kernel<<<grid_for((long long)Ntot * 16, 256), 256, 0, stream>>>(
        (const float4*)fu, (const float4*)fb, (const float4*)fi,
        nU, nB, nI, off1, off2, Ntot, isq, (ushort4*)bufA, (float4*)out);

    // --- 2 fused layers over the whole union ---
    unsigned short* cur = bufA;
    unsigned short* nxt = bufB;
    for (int layer = 0; layer < 2; ++layer) {
        int writeNext = (layer + 1 < 2) ? 1 : 0;
        spmm_norm_kernel<<<grid_for((long long)Ntot * EMB, 256), 256, 0, stream>>>(
            ptr8, ci, isq, cur, nxt, out, Ntot, writeNext);
        unsigned short* t = cur; cur = nxt; nxt = t;
    }
}

// Round 10
// 1903.526 us; speedup vs baseline: 1.2693x; 1.0022x over previous
//
#include <hip/hip_runtime.h>
#include <hip/hip_bf16.h>

// LightGCN propagation, 3 bipartite graphs. Round 9: XCD-local CSR atomics.
// Evidence (r1 vs r8): fire-and-forget atomics run ~75G/s, but the scatter's
// fetch-add NEEDS its return -> device-scope round-trip to memory-side
// (per-XCD L2s non-coherent) stalls every edge ~600-900cy. Fix: per-(node,
// XCD) counters/cursors indexed node*8+XCC_ID, so each counter is touched by
// ONE die only -> workgroup-scope atomic = L2-local RMW (8 L2s in parallel,
// ~4x lower latency). Scan over node-major/xcc-minor counters yields an
// EXACT CSR with per-row-contiguous ci (no padding); spmm reads
// ptr8[n*8]..ptr8[n*8+8]. Union-graph + bf16 features kept from r7/r8.

constexpr int EMB = 64;
constexpr int NXCD = 8;
constexpr float THIRD = 1.0f / 3.0f;
constexpr float EPS_NRM = 1e-12f;
constexpr float EPS_LAP = 1e-8f;
constexpr int SCAN_BLOCK = 256;
constexpr int SCAN_ITEMS = 16;       // = 2 nodes' worth of (node,xcd) counters
constexpr int SCAN_TILE = SCAN_BLOCK * SCAN_ITEMS;  // 4096

__device__ __forceinline__ unsigned short f2b(float x) {
    __hip_bfloat16 h = __float2bfloat16(x);
    return *reinterpret_cast<unsigned short*>(&h);
}
__device__ __forceinline__ float b2f(unsigned short u) {
    return __uint_as_float(((unsigned)u) << 16);
}
__device__ __forceinline__ int xcc_id() {
    unsigned x;
    asm volatile("s_getreg_b32 %0, hwreg(HW_REG_XCC_ID)" : "=s"(x));
    return (int)(x & (NXCD - 1));
}
__device__ __forceinline__ int fadd_local(int* p) {
    return __hip_atomic_fetch_add(p, 1, __ATOMIC_RELAXED,
                                  __HIP_MEMORY_SCOPE_WORKGROUP);
}

// 1 thread per directed edge; bump cnt8[node*8 + xcc] (L2-local, no return).
__global__ void hist3_kernel(const int* __restrict__ r0, const int* __restrict__ c0,
                             const int* __restrict__ r1, const int* __restrict__ c1,
                             const int* __restrict__ r2, const int* __restrict__ c2,
                             long long H0, long long H01, long long H,
                             int off1, int off2,
                             int* __restrict__ cnt) {
    long long t = blockIdx.x * (long long)blockDim.x + threadIdx.x;
    if (t >= 2 * H) return;
    const bool second = (t >= H);
    long long p = second ? t - H : t;
    int node;
    if (p < H0)       { node = second ? c0[p] : r0[p]; }
    else if (p < H01) { long long i = p - H0;  node = (second ? c1[i] : r1[i]) + off1; }
    else              { long long i = p - H01; node = (second ? c2[i] : r2[i]) + off2; }
    (void)fadd_local(&cnt[(long long)node * NXCD + xcc_id()]);
}

// --- two-level scan over N8 = Ntot*8 (node,xcd) counters --------------------
__global__ void scan_partial_kernel(const int* __restrict__ cnt, int N8,
                                    int* __restrict__ bsum) {
    __shared__ int red[SCAN_BLOCK];
    const int b = blockIdx.x;
    const int t = threadIdx.x;
    const int base = b * SCAN_TILE + t * SCAN_ITEMS;
    int s = 0;
    if (base + SCAN_ITEMS <= N8) {
        #pragma unroll
        for (int q = 0; q < 4; ++q) {
            int4 a = ((const int4*)cnt)[(base >> 2) + q];
            s += a.x + a.y + a.z + a.w;
        }
    } else {
        for (int k = 0; k < SCAN_ITEMS; ++k)
            if (base + k < N8) s += cnt[base + k];
    }
    red[t] = s;
    __syncthreads();
    for (int off = SCAN_BLOCK / 2; off > 0; off >>= 1) {
        if (t < off) red[t] += red[t + off];
        __syncthreads();
    }
    if (t == 0) bsum[b] = red[0];
}

__global__ void scan_bsums_kernel(int* __restrict__ bsum, int NB) {
    __shared__ int s[1024];
    const int t = threadIdx.x;
    int v = (t < NB) ? bsum[t] : 0;
    s[t] = v;
    __syncthreads();
    for (int off = 1; off < 1024; off <<= 1) {
        int x = (t >= off) ? s[t - off] : 0;
        __syncthreads();
        s[t] += x;
        __syncthreads();
    }
    if (t < NB) bsum[t] = s[t] - v;      // exclusive prefix
    if (t == 1023) bsum[NB] = s[1023];   // total
}

// Exclusive scan + cursor init; each thread owns exactly 2 nodes (16
// counters), so per-node degree = local 8-sum -> isq computed here.
__global__ void scan_apply_kernel(int* __restrict__ cnt, int N8,
                                  const int* __restrict__ bsum, int NB,
                                  int* __restrict__ ptr,
                                  float* __restrict__ isq) {
    __shared__ int tsum[SCAN_BLOCK];
    const int b = blockIdx.x;
    const int t = threadIdx.x;
    const int base = b * SCAN_TILE + t * SCAN_ITEMS;
    int v[SCAN_ITEMS];
    int s = 0;
    if (base + SCAN_ITEMS <= N8) {
        #pragma unroll
        for (int q = 0; q < 4; ++q) {
            int4 a = ((const int4*)cnt)[(base >> 2) + q];
            v[4 * q + 0] = a.x; v[4 * q + 1] = a.y;
            v[4 * q + 2] = a.z; v[4 * q + 3] = a.w;
        }
        #pragma unroll
        for (int k = 0; k < SCAN_ITEMS; ++k) s += v[k];
    } else {
        for (int k = 0; k < SCAN_ITEMS; ++k) {
            v[k] = (base + k < N8) ? cnt[base + k] : 0;
            s += v[k];
        }
    }
    tsum[t] = s;
    __syncthreads();
    for (int off = 1; off < SCAN_BLOCK; off <<= 1) {
        int x = (t >= off) ? tsum[t - off] : 0;
        __syncthreads();
        tsum[t] += x;
        __syncthreads();
    }
    int run = bsum[b] + tsum[t] - s;
    for (int k = 0; k < SCAN_ITEMS; ++k) {
        if (base + k < N8) {
            ptr[base + k] = run;
            cnt[base + k] = run;         // scatter cursor
            run += v[k];
        }
    }
    // base is a multiple of 16 and N8 a multiple of 8 -> full-node chunks.
    if (base < N8) {
        int d0 = v[0] + v[1] + v[2] + v[3] + v[4] + v[5] + v[6] + v[7];
        isq[base >> 3] = 1.0f / (sqrtf((float)d0) + EPS_LAP);
    }
    if (base + 8 < N8) {
        int d1 = v[8] + v[9] + v[10] + v[11] + v[12] + v[13] + v[14] + v[15];
        isq[(base >> 3) + 1] = 1.0f / (sqrtf((float)d1) + EPS_LAP);
    }
    if (b == 0 && t == 0) ptr[N8] = bsum[NB];
}
// ----------------------------------------------------------------------------

// 1 thread per directed edge: L2-local fetch-add on the (row,xcc) cursor +
// 1 scattered store. Positions are globally unique and row-contiguous.
__global__ void scatter3_kernel(const int* __restrict__ r0, const int* __restrict__ c0,
                                const int* __restrict__ r1, const int* __restrict__ c1,
                                const int* __restrict__ r2, const int* __restrict__ c2,
                                long long H0, long long H01, long long H,
                                int off1, int off2,
                                int* __restrict__ cursor,
                                int* __restrict__ ci) {
    long long t = blockIdx.x * (long long)blockDim.x + threadIdx.x;
    if (t >= 2 * H) return;
    const bool second = (t >= H);
    long long p = second ? t - H : t;
    int a, b;
    if (p < H0)       { a = r0[p];                  b = c0[p]; }
    else if (p < H01) { long long i = p - H0;  a = r1[i] + off1; b = c1[i] + off1; }
    else              { long long i = p - H01; a = r2[i] + off2; b = c2[i] + off2; }
    int row = second ? b : a;
    int col = second ? a : b;
    int pos = fadd_local(&cursor[(long long)row * NXCD + xcc_id()]);
    ci[pos] = col;
}

// Union init: node n -> (graph, A/B feature source). curS = bf16(isq*x);
// acc = x/3 (fp32, directly in d_out).
__global__ void init3_kernel(const float4* __restrict__ fu,
                             const float4* __restrict__ fb,
                             const float4* __restrict__ fi,
                             int nU, int nB, int nI,
                             int off1, int off2, int Ntot,
                             const float* __restrict__ isq,
                             ushort4* __restrict__ curS,
                             float4* __restrict__ acc) {
    long long total = (long long)Ntot * 16;
    long long i = blockIdx.x * (long long)blockDim.x + threadIdx.x;
    if (i >= total) return;
    int n = (int)(i >> 4);
    int ch = (int)(i & 15);
    float4 v;
    if (n < off1) {
        v = (n < nU) ? fu[(long long)n * 16 + ch]
                     : fb[(long long)(n - nU) * 16 + ch];
    } else if (n < off2) {
        int l = n - off1;
        v = (l < nU) ? fu[(long long)l * 16 + ch]
                     : fi[(long long)(l - nU) * 16 + ch];
    } else {
        int l = n - off2;
        v = (l < nB) ? fb[(long long)l * 16 + ch]
                     : fi[(long long)(l - nB) * 16 + ch];
    }
    float q = isq[n];
    curS[i] = make_ushort4(f2b(v.x * q), f2b(v.y * q), f2b(v.z * q), f2b(v.w * q));
    acc[i] = make_float4(v.x * THIRD, v.y * THIRD, v.z * THIRD, v.w * THIRD);
}

// One wave per union row; lane owns one dim. bf16 gathers (fp32 accumulate),
// 4-way unrolled; fused row-L2-norm + acc update; optional bf16 nxtS write.
// Row range: ptr8[n*8] .. ptr8[n*8+8].
__global__ void spmm_norm_kernel(const int* __restrict__ ptr8,
                                 const int* __restrict__ ci,
                                 const float* __restrict__ isq,
                                 const unsigned short* __restrict__ curS,
                                 unsigned short* __restrict__ nxtS,
                                 float* __restrict__ acc,
                                 int N, int writeNext) {
    int gid = (int)((blockIdx.x * (long long)blockDim.x + threadIdx.x) >> 6);
    int lane = threadIdx.x & 63;
    if (gid >= N) return;
    const int beg = ptr8[(long long)gid * NXCD];
    const int end = ptr8[(long long)gid * NXCD + NXCD];
    float s = 0.0f;
    int j = beg;
    for (; j + 4 <= end; j += 4) {
        int c0 = ci[j];
        int c1 = ci[j + 1];
        int c2 = ci[j + 2];
        int c3 = ci[j + 3];
        float g0 = b2f(curS[(long long)c0 * EMB + lane]);
        float g1 = b2f(curS[(long long)c1 * EMB + lane]);
        float g2 = b2f(curS[(long long)c2 * EMB + lane]);
        float g3 = b2f(curS[(long long)c3 * EMB + lane]);
        s += g0 + g1 + g2 + g3;
    }
    for (; j < end; ++j) {
        s += b2f(curS[(long long)ci[j] * EMB + lane]);
    }
    const float q = isq[gid];
    float raw = s * q;
    float ss = raw * raw;
    ss += __shfl_xor(ss, 1, 64);
    ss += __shfl_xor(ss, 2, 64);
    ss += __shfl_xor(ss, 4, 64);
    ss += __shfl_xor(ss, 8, 64);
    ss += __shfl_xor(ss, 16, 64);
    ss += __shfl_xor(ss, 32, 64);
    const long long idx = (long long)gid * EMB + lane;
    if (writeNext) nxtS[idx] = f2b(raw * q);
    float scale = THIRD / fmaxf(sqrtf(ss), EPS_NRM);
    acc[idx] += raw * scale;
}

static inline int grid_for(long long total, int block) {
    long long g = (total + block - 1) / block;
    if (g > (1LL << 20)) g = (1LL << 20);
    if (g < 1) g = 1;
    return (int)g;
}

extern "C" void kernel_launch(void* const* d_in, const int* in_sizes, int n_in,
                              void* d_out, int out_size, void* d_ws, size_t ws_size,
                              hipStream_t stream) {
    const float* fu = (const float*)d_in[0];
    const float* fb = (const float*)d_in[1];
    const float* fi = (const float*)d_in[2];
    const int nU = in_sizes[0] / EMB;
    const int nB = in_sizes[1] / EMB;
    const int nI = in_sizes[2] / EMB;
    float* out = (float*)d_out;

    // Union-graph geometry.
    const int N0 = nU + nB, N1 = nU + nI, N2 = nB + nI;
    const int off1 = N0;
    const int off2 = N0 + N1;
    const int Ntot = N0 + N1 + N2;
    const int N8 = Ntot * NXCD;
    const long long H0 = (long long)in_sizes[3] / 2;
    const long long H1 = (long long)in_sizes[6] / 2;
    const long long H2 = (long long)in_sizes[9] / 2;
    const long long H01 = H0 + H1;
    const long long H = H0 + H1 + H2;
    const int NB_ = (N8 + SCAN_TILE - 1) / SCAN_TILE;

    const int* r0 = (const int*)d_in[3];
    const int* c0 = (const int*)d_in[4];
    const int* r1 = (const int*)d_in[6];
    const int* c1 = (const int*)d_in[7];
    const int* r2 = (const int*)d_in[9];
    const int* c2 = (const int*)d_in[10];

    // Workspace layout (16B-aligned chunks): ~151MB total.
    char* w = (char*)d_ws;
    unsigned short* bufA = (unsigned short*)w;  w += (size_t)Ntot * EMB * sizeof(unsigned short);
    unsigned short* bufB = (unsigned short*)w;  w += (size_t)Ntot * EMB * sizeof(unsigned short);
    int* ptr8 = (int*)w;                        w += (size_t)(N8 + 16) * sizeof(int);
    int* cnt8 = (int*)w;                        w += (size_t)(N8 + 16) * sizeof(int);
    float* isq = (float*)w;                     w += (size_t)((Ntot + 8) & ~7) * sizeof(float);
    int* bsum = (int*)w;                        w += (size_t)((NB_ + 8) & ~7) * sizeof(int);
    int* ci = (int*)w;

    // --- CSR build over the union graph (XCD-local atomics) ---
    hipMemsetAsync(cnt8, 0, (size_t)N8 * sizeof(int), stream);
    hist3_kernel<<<grid_for(2 * H, 256), 256, 0, stream>>>(
        r0, c0, r1, c1, r2, c2, H0, H01, H, off1, off2, cnt8);
    scan_partial_kernel<<<NB_, SCAN_BLOCK, 0, stream>>>(cnt8, N8, bsum);
    scan_bsums_kernel<<<1, 1024, 0, stream>>>(bsum, NB_);
    scan_apply_kernel<<<NB_, SCAN_BLOCK, 0, stream>>>(cnt8, N8, bsum, NB_, ptr8, isq);
    scatter3_kernel<<<grid_for(2 * H, 256), 256, 0, stream>>>(
        r0, c0, r1, c1, r2, c2, H0, H01, H, off1, off2, cnt8, ci);

    // --- init: curS = bf16(isq.*x); acc = x/3 (into d_out) ---
    init3_kernel<<<grid_for((long long)Ntot * 16, 256), 256, 0, stream>>>(
        (const float4*)fu, (const float4*)fb, (const float4*)fi,
        nU, nB, nI, off1, off2, Ntot, isq, (ushort4*)bufA, (float4*)out);

    // --- 2 fused layers over the whole union ---
    unsigned short* cur = bufA;
    unsigned short* nxt = bufB;
    for (int layer = 0; layer < 2; ++layer) {
        int writeNext = (layer + 1 < 2) ? 1 : 0;
        spmm_norm_kernel<<<grid_for((long long)Ntot * EMB, 256), 256, 0, stream>>>(
            ptr8, ci, isq, cur, nxt, out, Ntot, writeNext);
        unsigned short* t = cur; cur = nxt; nxt = t;
    }
}